// Round 10
// baseline (425.580 us; speedup 1.0000x reference)
//
#include <hip/hip_runtime.h>

#define FIN 128
#define HID 64
#define OUTC 16
#define R1 16
#define BSH 8              // 256 nodes per bucket
#define MAXNB 512          // supports N <= 131072

__device__ __forceinline__ float lrelu_exp(float v) {
    v = (v > 0.f) ? v : 0.2f * v;
    return __expf(v);
}

// ---------------- K1: h1 = x @ W1 ; as1/ad1 = rowdot(h1, a_src/a_dst) ----------------
__global__ __launch_bounds__(256) void k1_gemm1(
    const float* __restrict__ x, const float* __restrict__ W1,
    const float* __restrict__ a_src, const float* __restrict__ a_dst,
    float* __restrict__ h1, float* __restrict__ as1, float* __restrict__ ad1, int N)
{
    __shared__ float Wlds[FIN * HID];   // 32 KB
    __shared__ float xlds[R1 * FIN];    // 8 KB
    int tid = threadIdx.x;
    const float4* W4 = (const float4*)W1;
    float4* Wl4 = (float4*)Wlds;
    #pragma unroll
    for (int i = tid; i < FIN * HID / 4; i += 256) Wl4[i] = W4[i];
    int row0 = blockIdx.x * R1;
    const float4* x4 = (const float4*)(x + (size_t)row0 * FIN);
    float4* xl4 = (float4*)xlds;
    for (int i = tid; i < R1 * FIN / 4; i += 256) {
        int r = row0 + (i >> 5);
        xl4[i] = (r < N) ? x4[i] : make_float4(0.f, 0.f, 0.f, 0.f);
    }
    __syncthreads();
    int col = tid & 63;
    int wv  = tid >> 6;        // 0..3, each wave owns 4 rows
    float acc[4] = {0.f, 0.f, 0.f, 0.f};
    const float4* xr0 = (const float4*)&xlds[(wv * 4 + 0) * FIN];
    const float4* xr1 = (const float4*)&xlds[(wv * 4 + 1) * FIN];
    const float4* xr2 = (const float4*)&xlds[(wv * 4 + 2) * FIN];
    const float4* xr3 = (const float4*)&xlds[(wv * 4 + 3) * FIN];
    #pragma unroll 4
    for (int k4 = 0; k4 < FIN / 4; ++k4) {
        float w0 = Wlds[(4 * k4 + 0) * HID + col];
        float w1 = Wlds[(4 * k4 + 1) * HID + col];
        float w2 = Wlds[(4 * k4 + 2) * HID + col];
        float w3 = Wlds[(4 * k4 + 3) * HID + col];
        float4 xv;
        xv = xr0[k4]; acc[0] += xv.x * w0 + xv.y * w1 + xv.z * w2 + xv.w * w3;
        xv = xr1[k4]; acc[1] += xv.x * w0 + xv.y * w1 + xv.z * w2 + xv.w * w3;
        xv = xr2[k4]; acc[2] += xv.x * w0 + xv.y * w1 + xv.z * w2 + xv.w * w3;
        xv = xr3[k4]; acc[3] += xv.x * w0 + xv.y * w1 + xv.z * w2 + xv.w * w3;
    }
    #pragma unroll
    for (int r = 0; r < 4; ++r) {
        int row = row0 + wv * 4 + r;
        if (row < N) {
            h1[(size_t)row * HID + col] = acc[r];
            float vs = acc[r] * a_src[col];
            float vd = acc[r] * a_dst[col];
            for (int off = 32; off > 0; off >>= 1) {
                vs += __shfl_down(vs, off);
                vd += __shfl_down(vd, off);
            }
            if (col == 0) { as1[row] = vs; ad1[row] = vd; }
        }
    }
}

// ---------------- bucket CSR build, phase 1: bucket histogram -----------------------
__global__ __launch_bounds__(256) void kp_cnt(
    const int* __restrict__ ei, int* __restrict__ bcnt, int E, int N)
{
    __shared__ int h[MAXNB];
    int tot = E + N;
    for (int i = threadIdx.x; i < MAXNB; i += 256) h[i] = 0;
    __syncthreads();
    int t0 = blockIdx.x * 4096;
    int n = min(4096, tot - t0);
    for (int i = threadIdx.x; i < n; i += 256) {
        int e = t0 + i;
        int d = (e < E) ? ei[E + e] : (e - E);
        atomicAdd(&h[d >> BSH], 1);
    }
    __syncthreads();
    int nb = (N + 255) >> BSH;
    for (int b = threadIdx.x; b < nb; b += 256)
        if (h[b]) atomicAdd(&bcnt[b], h[b]);
}

// ---------------- phase 2: scan bucket counts ---------------------------------------
__global__ __launch_bounds__(512) void kp_scan(
    const int* __restrict__ bcnt, int* __restrict__ bstartE, int* __restrict__ bcur, int N)
{
    __shared__ int sA[512], sB[512];
    int nb = (N + 255) >> BSH;
    int tid = threadIdx.x;
    int c = (tid < nb) ? bcnt[tid] : 0;
    sA[tid] = c;
    __syncthreads();
    int* src = sA; int* dst = sB;
    for (int off = 1; off < 512; off <<= 1) {
        int v = src[tid];
        if (tid >= off) v += src[tid - off];
        dst[tid] = v;
        __syncthreads();
        int* t = src; src = dst; dst = t;
    }
    int incl = src[tid];
    int excl = incl - c;
    if (tid < nb) {
        bstartE[tid] = excl;
        bcur[tid] = excl;
        if (tid == nb - 1) bstartE[nb] = incl;
    }
}

// ---------------- phase 3: tiled multi-split; packed 4B records ---------------------
// record = s | (local_d << 24): s < 2^24, local_d < 256
__global__ __launch_bounds__(256) void kp_part(
    const int* __restrict__ ei, int* __restrict__ bcur, unsigned* __restrict__ pairs,
    int E, int N)
{
    __shared__ unsigned pk[4096];                    // 16 KB
    __shared__ int bL[4096];                         // 16 KB
    __shared__ int cnt[MAXNB], base[MAXNB], wcur[MAXNB];
    int tot = E + N;
    for (int i = threadIdx.x; i < MAXNB; i += 256) { cnt[i] = 0; wcur[i] = 0; }
    int t0 = blockIdx.x * 4096;
    int n = min(4096, tot - t0);
    for (int i = threadIdx.x; i < n; i += 256) {
        int e = t0 + i; int s, d;
        if (e < E) { s = ei[e]; d = ei[E + e]; } else { s = d = e - E; }
        pk[i] = (unsigned)s | ((unsigned)(d & 255) << 24);
        bL[i] = d >> BSH;
    }
    __syncthreads();
    for (int i = threadIdx.x; i < n; i += 256) atomicAdd(&cnt[bL[i]], 1);
    __syncthreads();
    int nb = (N + 255) >> BSH;
    for (int b = threadIdx.x; b < nb; b += 256) {
        int c = cnt[b];
        if (c) base[b] = atomicAdd(&bcur[b], c);
    }
    __syncthreads();
    for (int i = threadIdx.x; i < n; i += 256) {
        int b = bL[i];
        int r = atomicAdd(&wcur[b], 1);
        pairs[base[b] + r] = pk[i];
    }
}

// ---------------- phase 4: per-bucket fine scatter + rowstart/counts ----------------
__global__ __launch_bounds__(256) void kc_fine(
    const unsigned* __restrict__ pairs, const int* __restrict__ bstartE,
    int* __restrict__ rowstart, int* __restrict__ counts, int* __restrict__ ssrc, int N)
{
    __shared__ int ncnt[256], nsA[256], nsB[256], nst[256];
    int blk = blockIdx.x, tid = threadIdx.x;
    int node0 = blk << BSH;
    int e0 = bstartE[blk], e1 = bstartE[blk + 1];
    ncnt[tid] = 0;
    __syncthreads();
    for (int i = e0 + tid; i < e1; i += 256)
        atomicAdd(&ncnt[pairs[i] >> 24], 1);
    __syncthreads();
    int c = ncnt[tid];
    nsA[tid] = c;
    __syncthreads();
    int* s = nsA; int* d = nsB;
    for (int off = 1; off < 256; off <<= 1) {
        int v = s[tid];
        if (tid >= off) v += s[tid - off];
        d[tid] = v;
        __syncthreads();
        int* t = s; s = d; d = t;
    }
    int excl = s[tid] - c;
    int node = node0 + tid;
    if (node < N) { rowstart[node] = e0 + excl; counts[node] = c; }
    __syncthreads();
    nst[tid] = excl;
    ncnt[tid] = 0;
    __syncthreads();
    for (int i = e0 + tid; i < e1; i += 256) {
        unsigned p = pairs[i];
        int dl = (int)(p >> 24);
        int r = atomicAdd(&ncnt[dl], 1);
        ssrc[e0 + nst[dl] + r] = (int)(p & 0xFFFFFFu);
    }
}

// ---------------- per-node normalized attention weights -----------------------------
__global__ __launch_bounds__(256) void k_wnorm(
    const int* __restrict__ rowstart, const int* __restrict__ counts,
    const int* __restrict__ ssrc, const float* __restrict__ as, const float* __restrict__ ad,
    float* __restrict__ alpha, int N)
{
    int n = blockIdx.x * 256 + threadIdx.x;
    if (n >= N) return;
    int start = rowstart[n];
    int deg   = counts[n];
    float adv = ad[n];
    float den = 0.f;
    int j = 0;
    for (; j + 4 <= deg; j += 4) {
        int s0 = ssrc[start + j + 0];
        int s1 = ssrc[start + j + 1];
        int s2 = ssrc[start + j + 2];
        int s3 = ssrc[start + j + 3];
        float w0 = lrelu_exp(as[s0] + adv);
        float w1 = lrelu_exp(as[s1] + adv);
        float w2 = lrelu_exp(as[s2] + adv);
        float w3 = lrelu_exp(as[s3] + adv);
        alpha[start + j + 0] = w0;
        alpha[start + j + 1] = w1;
        alpha[start + j + 2] = w2;
        alpha[start + j + 3] = w3;
        den += (w0 + w1) + (w2 + w3);
    }
    for (; j < deg; ++j) {
        int s = ssrc[start + j];
        float w = lrelu_exp(as[s] + adv);
        alpha[start + j] = w;
        den += w;
    }
    float inv = 1.f / (den + 1e-16f);
    j = 0;
    for (; j + 4 <= deg; j += 4) {
        alpha[start + j + 0] *= inv;
        alpha[start + j + 1] *= inv;
        alpha[start + j + 2] *= inv;
        alpha[start + j + 3] *= inv;
    }
    for (; j < deg; ++j) alpha[start + j] *= inv;
}

// ---------------- GAT gather layer 1 (C=64): wave per node, 8 edges in flight -------
__global__ __launch_bounds__(256) void k_gat1(
    const int* __restrict__ rowstart, const int* __restrict__ counts,
    const int* __restrict__ ssrc, const float* __restrict__ alpha,
    const float* __restrict__ h, float* __restrict__ outp, int N)
{
    int wid = (blockIdx.x * 256 + threadIdx.x) >> 6;   // node
    int lane = threadIdx.x & 63;                       // channel
    if (wid >= N) return;
    int start = rowstart[wid];
    int deg   = counts[wid];
    float acc = 0.f;
    int j = 0;
    for (; j + 8 <= deg; j += 8) {
        int s0 = ssrc[start + j + 0];
        int s1 = ssrc[start + j + 1];
        int s2 = ssrc[start + j + 2];
        int s3 = ssrc[start + j + 3];
        int s4 = ssrc[start + j + 4];
        int s5 = ssrc[start + j + 5];
        int s6 = ssrc[start + j + 6];
        int s7 = ssrc[start + j + 7];
        float a0 = alpha[start + j + 0];
        float a1 = alpha[start + j + 1];
        float a2 = alpha[start + j + 2];
        float a3 = alpha[start + j + 3];
        float a4 = alpha[start + j + 4];
        float a5 = alpha[start + j + 5];
        float a6 = alpha[start + j + 6];
        float a7 = alpha[start + j + 7];
        float h0 = h[(size_t)s0 * HID + lane];
        float h1v = h[(size_t)s1 * HID + lane];
        float h2v = h[(size_t)s2 * HID + lane];
        float h3v = h[(size_t)s3 * HID + lane];
        float h4 = h[(size_t)s4 * HID + lane];
        float h5 = h[(size_t)s5 * HID + lane];
        float h6 = h[(size_t)s6 * HID + lane];
        float h7 = h[(size_t)s7 * HID + lane];
        acc += a0 * h0;  acc += a1 * h1v;
        acc += a2 * h2v; acc += a3 * h3v;
        acc += a4 * h4;  acc += a5 * h5;
        acc += a6 * h6;  acc += a7 * h7;
    }
    for (; j < deg; ++j) {
        int s = ssrc[start + j];
        acc += alpha[start + j] * h[(size_t)s * HID + lane];
    }
    outp[(size_t)wid * HID + lane] = acc;
}

// ---------------- K4: relu(out1+b1) @ W2 ; as2/ad2 -----------------------------------
__global__ __launch_bounds__(256) void k4_gemm2(
    const float* __restrict__ out1, const float* __restrict__ b1,
    const float* __restrict__ W2, const float* __restrict__ a_src, const float* __restrict__ a_dst,
    float* __restrict__ h2, float* __restrict__ as2, float* __restrict__ ad2, int N)
{
    __shared__ float Wlds[HID * OUTC];   // 4 KB
    __shared__ float rlds[16 * HID];     // 4 KB
    int tid = threadIdx.x;
    for (int i = tid; i < HID * OUTC; i += 256) Wlds[i] = W2[i];
    int row0 = blockIdx.x * 16;
    for (int i = tid; i < 16 * HID; i += 256) {
        int r = row0 + (i >> 6);
        float v = (r < N) ? out1[(size_t)r * HID + (i & 63)] : 0.f;
        v += b1[i & 63];
        rlds[i] = fmaxf(v, 0.f);
    }
    __syncthreads();
    int col = tid & 15;
    int rl  = tid >> 4;
    int row = row0 + rl;
    float acc = 0.f;
    #pragma unroll 8
    for (int k = 0; k < HID; ++k)
        acc += rlds[rl * HID + k] * Wlds[k * OUTC + col];
    if (row < N) {
        h2[(size_t)row * OUTC + col] = acc;
        float vs = acc * a_src[col];
        float vd = acc * a_dst[col];
        for (int off = 8; off > 0; off >>= 1) {
            vs += __shfl_down(vs, off, 16);
            vd += __shfl_down(vd, off, 16);
        }
        if (col == 0) { as2[row] = vs; ad2[row] = vd; }
    }
}

// ---------------- GAT gather layer 2 (C=16): wave per node, 8 edges in flight -------
__global__ __launch_bounds__(256) void k_gat2(
    const int* __restrict__ rowstart, const int* __restrict__ counts,
    const int* __restrict__ ssrc, const float* __restrict__ alpha,
    const float* __restrict__ h, float* __restrict__ outp, int N)
{
    int wid = (blockIdx.x * 256 + threadIdx.x) >> 6;   // node
    int lane = threadIdx.x & 63;
    int c  = lane & 15;       // channel
    int eo = lane >> 4;       // edge subgroup 0..3
    if (wid >= N) return;
    int start = rowstart[wid];
    int deg   = counts[wid];
    float acc = 0.f;
    int j = eo;
    for (; j + 4 < deg; j += 8) {
        int s0 = ssrc[start + j];
        int s1 = ssrc[start + j + 4];
        float a0 = alpha[start + j];
        float a1 = alpha[start + j + 4];
        float h0 = h[(size_t)s0 * OUTC + c];
        float h1v = h[(size_t)s1 * OUTC + c];
        acc += a0 * h0;
        acc += a1 * h1v;
    }
    if (j < deg) {
        int s = ssrc[start + j];
        acc += alpha[start + j] * h[(size_t)s * OUTC + c];
    }
    acc += __shfl_xor(acc, 16);
    acc += __shfl_xor(acc, 32);
    if (eo == 0) outp[(size_t)wid * OUTC + c] = acc;
}

// ---------------- K7: per-node MLP 16->64->16 + softmax ------------------------------
__global__ __launch_bounds__(256) void k7_mlp(
    const float* __restrict__ out2, const float* __restrict__ b2,
    const float* __restrict__ lin1W, const float* __restrict__ lin1b,
    const float* __restrict__ lin2W, const float* __restrict__ lin2b,
    float* __restrict__ out, int N)
{
    __shared__ float W1l[OUTC * HID];   // 4 KB
    __shared__ float W2l[HID * OUTC];   // 4 KB
    __shared__ float b1l[HID], bb2[OUTC], b2l[OUTC];
    int tid = threadIdx.x;
    for (int i = tid; i < OUTC * HID; i += 256) { W1l[i] = lin1W[i]; W2l[i] = lin2W[i]; }
    if (tid < HID) b1l[tid] = lin1b[tid];
    if (tid < OUTC) { bb2[tid] = b2[tid]; b2l[tid] = lin2b[tid]; }
    __syncthreads();
    int n = blockIdx.x * 256 + tid;
    if (n >= N) return;

    float o[OUTC];
    const float4* o4 = (const float4*)(out2 + (size_t)n * OUTC);
    #pragma unroll
    for (int i = 0; i < 4; ++i) {
        float4 v = o4[i];
        o[4*i+0] = v.x + bb2[4*i+0];
        o[4*i+1] = v.y + bb2[4*i+1];
        o[4*i+2] = v.z + bb2[4*i+2];
        o[4*i+3] = v.w + bb2[4*i+3];
    }
    float u[OUTC];
    #pragma unroll
    for (int c = 0; c < OUTC; ++c) u[c] = b2l[c];
    for (int j = 0; j < HID; ++j) {
        float t = b1l[j];
        #pragma unroll
        for (int i = 0; i < OUTC; ++i) t += o[i] * W1l[i * HID + j];
        t = fmaxf(t, 0.f);
        #pragma unroll
        for (int c = 0; c < OUTC; ++c) u[c] += t * W2l[j * OUTC + c];
    }
    float m = u[0];
    #pragma unroll
    for (int c = 1; c < OUTC; ++c) m = fmaxf(m, u[c]);
    float sum = 0.f;
    #pragma unroll
    for (int c = 0; c < OUTC; ++c) { u[c] = __expf(u[c] - m); sum += u[c]; }
    float inv = 1.f / sum;
    float4* dst4 = (float4*)(out + (size_t)n * OUTC);
    #pragma unroll
    for (int i = 0; i < 4; ++i) {
        float4 v;
        v.x = u[4*i+0] * inv; v.y = u[4*i+1] * inv;
        v.z = u[4*i+2] * inv; v.w = u[4*i+3] * inv;
        dst4[i] = v;
    }
}

extern "C" void kernel_launch(void* const* d_in, const int* in_sizes, int n_in,
                              void* d_out, int out_size, void* d_ws, size_t ws_size,
                              hipStream_t stream)
{
    const float* x      = (const float*)d_in[0];
    const int*   ei     = (const int*)  d_in[1];
    const float* W1     = (const float*)d_in[2];
    const float* a_src1 = (const float*)d_in[3];
    const float* a_dst1 = (const float*)d_in[4];
    const float* b1     = (const float*)d_in[5];
    const float* W2     = (const float*)d_in[6];
    const float* a_src2 = (const float*)d_in[7];
    const float* a_dst2 = (const float*)d_in[8];
    const float* b2     = (const float*)d_in[9];
    const float* lin1W  = (const float*)d_in[10];
    const float* lin1b  = (const float*)d_in[11];
    const float* lin2W  = (const float*)d_in[12];
    const float* lin2b  = (const float*)d_in[13];
    float* out = (float*)d_out;

    int N = in_sizes[0] / FIN;
    int E = in_sizes[1] / 2;
    int tot = E + N;
    int nb = (N + 255) >> BSH;
    int ntile = (tot + 4095) / 4096;

    float* ws = (float*)d_ws;
    size_t off = 0;
    float* h1    = ws + off; off += (size_t)N * HID;
    float* out1  = ws + off; off += (size_t)N * HID;   // pairs aliases this region
    float* as1   = ws + off; off += N;
    float* ad1   = ws + off; off += N;
    float* h2    = ws + off; off += (size_t)N * OUTC;
    float* out2  = ws + off; off += (size_t)N * OUTC;
    float* as2   = ws + off; off += N;
    float* ad2   = ws + off; off += N;
    float* alpha = ws + off; off += tot;
    int* rowstart = (int*)(ws + off); off += N;
    int* counts   = (int*)(ws + off); off += N;
    int* ssrc     = (int*)(ws + off); off += tot;
    int* bcnt     = (int*)(ws + off); off += MAXNB;
    int* bstartE  = (int*)(ws + off); off += MAXNB + 1;
    int* bcur     = (int*)(ws + off); off += MAXNB;
    unsigned* pairs = (unsigned*)out1;  // 6.8 MB <= 25.6 MB, consumed before k_gat1 writes out1

    hipMemsetAsync(bcnt, 0, (size_t)nb * sizeof(int), stream);

    // bucketed CSR build (packed 4B records)
    kp_cnt <<<ntile, 256, 0, stream>>>(ei, bcnt, E, N);
    kp_scan<<<1, 512, 0, stream>>>(bcnt, bstartE, bcur, N);
    kp_part<<<ntile, 256, 0, stream>>>(ei, bcur, pairs, E, N);
    kc_fine<<<nb, 256, 0, stream>>>(pairs, bstartE, rowstart, counts, ssrc, N);

    // layer 1
    k1_gemm1<<<(N + R1 - 1) / R1, 256, 0, stream>>>(x, W1, a_src1, a_dst1, h1, as1, ad1, N);
    k_wnorm <<<(N + 255) / 256, 256, 0, stream>>>(rowstart, counts, ssrc, as1, ad1, alpha, N);
    k_gat1  <<<(N + 3) / 4, 256, 0, stream>>>(rowstart, counts, ssrc, alpha, h1, out1, N);

    // layer 2
    k4_gemm2<<<(N + 15) / 16, 256, 0, stream>>>(out1, b1, W2, a_src2, a_dst2, h2, as2, ad2, N);
    k_wnorm <<<(N + 255) / 256, 256, 0, stream>>>(rowstart, counts, ssrc, as2, ad2, alpha, N);
    k_gat2  <<<(N + 3) / 4, 256, 0, stream>>>(rowstart, counts, ssrc, alpha, h2, out2, N);

    // MLP + softmax
    k7_mlp<<<(N + 255) / 256, 256, 0, stream>>>(out2, b2, lin1W, lin1b, lin2W, lin2b, out, N);
}

// Round 11
// 405.803 us; speedup vs baseline: 1.0487x; 1.0487x over previous
//
#include <hip/hip_runtime.h>
#include <hip/hip_fp16.h>

#define FIN 128
#define HID 64
#define OUTC 16
#define R1 16
#define BSH 8              // 256 nodes per bucket
#define MAXNB 512          // supports N <= 131072

__device__ __forceinline__ float lrelu_exp(float v) {
    v = (v > 0.f) ? v : 0.2f * v;
    return __expf(v);
}

// ---------------- K1: h1(fp16) = x @ W1 ; as1/ad1 = rowdot(h1, a_src/a_dst) ---------
__global__ __launch_bounds__(256) void k1_gemm1(
    const float* __restrict__ x, const float* __restrict__ W1,
    const float* __restrict__ a_src, const float* __restrict__ a_dst,
    __half* __restrict__ h1, float* __restrict__ as1, float* __restrict__ ad1, int N)
{
    __shared__ float Wlds[FIN * HID];   // 32 KB
    __shared__ float xlds[R1 * FIN];    // 8 KB
    int tid = threadIdx.x;
    const float4* W4 = (const float4*)W1;
    float4* Wl4 = (float4*)Wlds;
    #pragma unroll
    for (int i = tid; i < FIN * HID / 4; i += 256) Wl4[i] = W4[i];
    int row0 = blockIdx.x * R1;
    const float4* x4 = (const float4*)(x + (size_t)row0 * FIN);
    float4* xl4 = (float4*)xlds;
    for (int i = tid; i < R1 * FIN / 4; i += 256) {
        int r = row0 + (i >> 5);
        xl4[i] = (r < N) ? x4[i] : make_float4(0.f, 0.f, 0.f, 0.f);
    }
    __syncthreads();
    int col = tid & 63;
    int wv  = tid >> 6;        // 0..3, each wave owns 4 rows
    float acc[4] = {0.f, 0.f, 0.f, 0.f};
    const float4* xr0 = (const float4*)&xlds[(wv * 4 + 0) * FIN];
    const float4* xr1 = (const float4*)&xlds[(wv * 4 + 1) * FIN];
    const float4* xr2 = (const float4*)&xlds[(wv * 4 + 2) * FIN];
    const float4* xr3 = (const float4*)&xlds[(wv * 4 + 3) * FIN];
    #pragma unroll 4
    for (int k4 = 0; k4 < FIN / 4; ++k4) {
        float w0 = Wlds[(4 * k4 + 0) * HID + col];
        float w1 = Wlds[(4 * k4 + 1) * HID + col];
        float w2 = Wlds[(4 * k4 + 2) * HID + col];
        float w3 = Wlds[(4 * k4 + 3) * HID + col];
        float4 xv;
        xv = xr0[k4]; acc[0] += xv.x * w0 + xv.y * w1 + xv.z * w2 + xv.w * w3;
        xv = xr1[k4]; acc[1] += xv.x * w0 + xv.y * w1 + xv.z * w2 + xv.w * w3;
        xv = xr2[k4]; acc[2] += xv.x * w0 + xv.y * w1 + xv.z * w2 + xv.w * w3;
        xv = xr3[k4]; acc[3] += xv.x * w0 + xv.y * w1 + xv.z * w2 + xv.w * w3;
    }
    #pragma unroll
    for (int r = 0; r < 4; ++r) {
        int row = row0 + wv * 4 + r;
        if (row < N) {
            h1[(size_t)row * HID + col] = __float2half(acc[r]);
            float vs = acc[r] * a_src[col];
            float vd = acc[r] * a_dst[col];
            for (int off = 32; off > 0; off >>= 1) {
                vs += __shfl_down(vs, off);
                vd += __shfl_down(vd, off);
            }
            if (col == 0) { as1[row] = vs; ad1[row] = vd; }
        }
    }
}

// ---------------- bucket CSR build, phase 1: bucket histogram -----------------------
__global__ __launch_bounds__(256) void kp_cnt(
    const int* __restrict__ ei, int* __restrict__ bcnt, int E, int N)
{
    __shared__ int h[MAXNB];
    int tot = E + N;
    for (int i = threadIdx.x; i < MAXNB; i += 256) h[i] = 0;
    __syncthreads();
    int t0 = blockIdx.x * 4096;
    int n = min(4096, tot - t0);
    for (int i = threadIdx.x; i < n; i += 256) {
        int e = t0 + i;
        int d = (e < E) ? ei[E + e] : (e - E);
        atomicAdd(&h[d >> BSH], 1);
    }
    __syncthreads();
    int nb = (N + 255) >> BSH;
    for (int b = threadIdx.x; b < nb; b += 256)
        if (h[b]) atomicAdd(&bcnt[b], h[b]);
}

// ---------------- phase 2: scan bucket counts ---------------------------------------
__global__ __launch_bounds__(512) void kp_scan(
    const int* __restrict__ bcnt, int* __restrict__ bstartE, int* __restrict__ bcur, int N)
{
    __shared__ int sA[512], sB[512];
    int nb = (N + 255) >> BSH;
    int tid = threadIdx.x;
    int c = (tid < nb) ? bcnt[tid] : 0;
    sA[tid] = c;
    __syncthreads();
    int* src = sA; int* dst = sB;
    for (int off = 1; off < 512; off <<= 1) {
        int v = src[tid];
        if (tid >= off) v += src[tid - off];
        dst[tid] = v;
        __syncthreads();
        int* t = src; src = dst; dst = t;
    }
    int incl = src[tid];
    int excl = incl - c;
    if (tid < nb) {
        bstartE[tid] = excl;
        bcur[tid] = excl;
        if (tid == nb - 1) bstartE[nb] = incl;
    }
}

// ---------------- phase 3: tiled multi-split; packed 4B records ---------------------
// record = s | (local_d << 24): s < 2^24, local_d < 256
__global__ __launch_bounds__(256) void kp_part(
    const int* __restrict__ ei, int* __restrict__ bcur, unsigned* __restrict__ pairs,
    int E, int N)
{
    __shared__ unsigned pk[4096];                    // 16 KB
    __shared__ unsigned short bL[4096];              // 8 KB
    __shared__ int cnt[MAXNB], base[MAXNB], wcur[MAXNB];
    int tot = E + N;
    for (int i = threadIdx.x; i < MAXNB; i += 256) { cnt[i] = 0; wcur[i] = 0; }
    int t0 = blockIdx.x * 4096;
    int n = min(4096, tot - t0);
    for (int i = threadIdx.x; i < n; i += 256) {
        int e = t0 + i; int s, d;
        if (e < E) { s = ei[e]; d = ei[E + e]; } else { s = d = e - E; }
        pk[i] = (unsigned)s | ((unsigned)(d & 255) << 24);
        bL[i] = (unsigned short)(d >> BSH);
    }
    __syncthreads();
    for (int i = threadIdx.x; i < n; i += 256) atomicAdd(&cnt[bL[i]], 1);
    __syncthreads();
    int nb = (N + 255) >> BSH;
    for (int b = threadIdx.x; b < nb; b += 256) {
        int c = cnt[b];
        if (c) base[b] = atomicAdd(&bcur[b], c);
    }
    __syncthreads();
    for (int i = threadIdx.x; i < n; i += 256) {
        int b = bL[i];
        int r = atomicAdd(&wcur[b], 1);
        pairs[base[b] + r] = pk[i];
    }
}

// ---------------- phase 4: per-bucket fine scatter + rowstart/counts ----------------
__global__ __launch_bounds__(256) void kc_fine(
    const unsigned* __restrict__ pairs, const int* __restrict__ bstartE,
    int* __restrict__ rowstart, int* __restrict__ counts, int* __restrict__ ssrc, int N)
{
    __shared__ int ncnt[256], nsA[256], nsB[256], nst[256];
    int blk = blockIdx.x, tid = threadIdx.x;
    int node0 = blk << BSH;
    int e0 = bstartE[blk], e1 = bstartE[blk + 1];
    ncnt[tid] = 0;
    __syncthreads();
    for (int i = e0 + tid; i < e1; i += 256)
        atomicAdd(&ncnt[pairs[i] >> 24], 1);
    __syncthreads();
    int c = ncnt[tid];
    nsA[tid] = c;
    __syncthreads();
    int* s = nsA; int* d = nsB;
    for (int off = 1; off < 256; off <<= 1) {
        int v = s[tid];
        if (tid >= off) v += s[tid - off];
        d[tid] = v;
        __syncthreads();
        int* t = s; s = d; d = t;
    }
    int excl = s[tid] - c;
    int node = node0 + tid;
    if (node < N) { rowstart[node] = e0 + excl; counts[node] = c; }
    __syncthreads();
    nst[tid] = excl;
    ncnt[tid] = 0;
    __syncthreads();
    for (int i = e0 + tid; i < e1; i += 256) {
        unsigned p = pairs[i];
        int dl = (int)(p >> 24);
        int r = atomicAdd(&ncnt[dl], 1);
        ssrc[e0 + nst[dl] + r] = (int)(p & 0xFFFFFFu);
    }
}

// ---------------- per-node attention weights (unnormalized) + inv denom -------------
__global__ __launch_bounds__(256) void k_wnorm(
    const int* __restrict__ rowstart, const int* __restrict__ counts,
    const int* __restrict__ ssrc, const float* __restrict__ as, const float* __restrict__ ad,
    float* __restrict__ alpha, float* __restrict__ invden, int N)
{
    int n = blockIdx.x * 256 + threadIdx.x;
    if (n >= N) return;
    int start = rowstart[n];
    int deg   = counts[n];
    float adv = ad[n];
    float den = 0.f;
    int j = 0;
    for (; j + 4 <= deg; j += 4) {
        int s0 = ssrc[start + j + 0];
        int s1 = ssrc[start + j + 1];
        int s2 = ssrc[start + j + 2];
        int s3 = ssrc[start + j + 3];
        float w0 = lrelu_exp(as[s0] + adv);
        float w1 = lrelu_exp(as[s1] + adv);
        float w2 = lrelu_exp(as[s2] + adv);
        float w3 = lrelu_exp(as[s3] + adv);
        alpha[start + j + 0] = w0;
        alpha[start + j + 1] = w1;
        alpha[start + j + 2] = w2;
        alpha[start + j + 3] = w3;
        den += (w0 + w1) + (w2 + w3);
    }
    for (; j < deg; ++j) {
        int s = ssrc[start + j];
        float w = lrelu_exp(as[s] + adv);
        alpha[start + j] = w;
        den += w;
    }
    invden[n] = 1.f / (den + 1e-16f);
}

// ---------------- GAT gather layer 1 (C=64, fp16 h): wave per node, 8 in flight -----
__global__ __launch_bounds__(256) void k_gat1(
    const int* __restrict__ rowstart, const int* __restrict__ counts,
    const int* __restrict__ ssrc, const float* __restrict__ alpha,
    const float* __restrict__ invden,
    const __half* __restrict__ h, float* __restrict__ outp, int N)
{
    int wid = (blockIdx.x * 256 + threadIdx.x) >> 6;   // node
    int lane = threadIdx.x & 63;                       // channel
    if (wid >= N) return;
    int start = rowstart[wid];
    int deg   = counts[wid];
    float acc = 0.f;
    int j = 0;
    for (; j + 8 <= deg; j += 8) {
        int s0 = ssrc[start + j + 0];
        int s1 = ssrc[start + j + 1];
        int s2 = ssrc[start + j + 2];
        int s3 = ssrc[start + j + 3];
        int s4 = ssrc[start + j + 4];
        int s5 = ssrc[start + j + 5];
        int s6 = ssrc[start + j + 6];
        int s7 = ssrc[start + j + 7];
        float a0 = alpha[start + j + 0];
        float a1 = alpha[start + j + 1];
        float a2 = alpha[start + j + 2];
        float a3 = alpha[start + j + 3];
        float a4 = alpha[start + j + 4];
        float a5 = alpha[start + j + 5];
        float a6 = alpha[start + j + 6];
        float a7 = alpha[start + j + 7];
        float h0 = __half2float(h[(size_t)s0 * HID + lane]);
        float h1v = __half2float(h[(size_t)s1 * HID + lane]);
        float h2v = __half2float(h[(size_t)s2 * HID + lane]);
        float h3v = __half2float(h[(size_t)s3 * HID + lane]);
        float h4 = __half2float(h[(size_t)s4 * HID + lane]);
        float h5 = __half2float(h[(size_t)s5 * HID + lane]);
        float h6 = __half2float(h[(size_t)s6 * HID + lane]);
        float h7 = __half2float(h[(size_t)s7 * HID + lane]);
        acc += a0 * h0;  acc += a1 * h1v;
        acc += a2 * h2v; acc += a3 * h3v;
        acc += a4 * h4;  acc += a5 * h5;
        acc += a6 * h6;  acc += a7 * h7;
    }
    for (; j < deg; ++j) {
        int s = ssrc[start + j];
        acc += alpha[start + j] * __half2float(h[(size_t)s * HID + lane]);
    }
    outp[(size_t)wid * HID + lane] = acc * invden[wid];
}

// ---------------- K4: relu(out1+b1) @ W2 ; as2/ad2 -----------------------------------
__global__ __launch_bounds__(256) void k4_gemm2(
    const float* __restrict__ out1, const float* __restrict__ b1,
    const float* __restrict__ W2, const float* __restrict__ a_src, const float* __restrict__ a_dst,
    float* __restrict__ h2, float* __restrict__ as2, float* __restrict__ ad2, int N)
{
    __shared__ float Wlds[HID * OUTC];   // 4 KB
    __shared__ float rlds[16 * HID];     // 4 KB
    int tid = threadIdx.x;
    for (int i = tid; i < HID * OUTC; i += 256) Wlds[i] = W2[i];
    int row0 = blockIdx.x * 16;
    for (int i = tid; i < 16 * HID; i += 256) {
        int r = row0 + (i >> 6);
        float v = (r < N) ? out1[(size_t)r * HID + (i & 63)] : 0.f;
        v += b1[i & 63];
        rlds[i] = fmaxf(v, 0.f);
    }
    __syncthreads();
    int col = tid & 15;
    int rl  = tid >> 4;
    int row = row0 + rl;
    float acc = 0.f;
    #pragma unroll 8
    for (int k = 0; k < HID; ++k)
        acc += rlds[rl * HID + k] * Wlds[k * OUTC + col];
    if (row < N) {
        h2[(size_t)row * OUTC + col] = acc;
        float vs = acc * a_src[col];
        float vd = acc * a_dst[col];
        for (int off = 8; off > 0; off >>= 1) {
            vs += __shfl_down(vs, off, 16);
            vd += __shfl_down(vd, off, 16);
        }
        if (col == 0) { as2[row] = vs; ad2[row] = vd; }
    }
}

// ---------------- GAT gather layer 2 (C=16): wave per node, 8 edges in flight -------
__global__ __launch_bounds__(256) void k_gat2(
    const int* __restrict__ rowstart, const int* __restrict__ counts,
    const int* __restrict__ ssrc, const float* __restrict__ alpha,
    const float* __restrict__ invden,
    const float* __restrict__ h, float* __restrict__ outp, int N)
{
    int wid = (blockIdx.x * 256 + threadIdx.x) >> 6;   // node
    int lane = threadIdx.x & 63;
    int c  = lane & 15;       // channel
    int eo = lane >> 4;       // edge subgroup 0..3
    if (wid >= N) return;
    int start = rowstart[wid];
    int deg   = counts[wid];
    float acc = 0.f;
    int j = eo;
    for (; j + 4 < deg; j += 8) {
        int s0 = ssrc[start + j];
        int s1 = ssrc[start + j + 4];
        float a0 = alpha[start + j];
        float a1 = alpha[start + j + 4];
        float h0 = h[(size_t)s0 * OUTC + c];
        float h1v = h[(size_t)s1 * OUTC + c];
        acc += a0 * h0;
        acc += a1 * h1v;
    }
    if (j < deg) {
        int s = ssrc[start + j];
        acc += alpha[start + j] * h[(size_t)s * OUTC + c];
    }
    acc += __shfl_xor(acc, 16);
    acc += __shfl_xor(acc, 32);
    if (eo == 0) outp[(size_t)wid * OUTC + c] = acc * invden[wid];
}

// ---------------- K7: per-node MLP 16->64->16 + softmax ------------------------------
__global__ __launch_bounds__(256) void k7_mlp(
    const float* __restrict__ out2, const float* __restrict__ b2,
    const float* __restrict__ lin1W, const float* __restrict__ lin1b,
    const float* __restrict__ lin2W, const float* __restrict__ lin2b,
    float* __restrict__ out, int N)
{
    __shared__ float W1l[OUTC * HID];   // 4 KB
    __shared__ float W2l[HID * OUTC];   // 4 KB
    __shared__ float b1l[HID], bb2[OUTC], b2l[OUTC];
    int tid = threadIdx.x;
    for (int i = tid; i < OUTC * HID; i += 256) { W1l[i] = lin1W[i]; W2l[i] = lin2W[i]; }
    if (tid < HID) b1l[tid] = lin1b[tid];
    if (tid < OUTC) { bb2[tid] = b2[tid]; b2l[tid] = lin2b[tid]; }
    __syncthreads();
    int n = blockIdx.x * 256 + tid;
    if (n >= N) return;

    float o[OUTC];
    const float4* o4 = (const float4*)(out2 + (size_t)n * OUTC);
    #pragma unroll
    for (int i = 0; i < 4; ++i) {
        float4 v = o4[i];
        o[4*i+0] = v.x + bb2[4*i+0];
        o[4*i+1] = v.y + bb2[4*i+1];
        o[4*i+2] = v.z + bb2[4*i+2];
        o[4*i+3] = v.w + bb2[4*i+3];
    }
    float u[OUTC];
    #pragma unroll
    for (int c = 0; c < OUTC; ++c) u[c] = b2l[c];
    for (int j = 0; j < HID; ++j) {
        float t = b1l[j];
        #pragma unroll
        for (int i = 0; i < OUTC; ++i) t += o[i] * W1l[i * HID + j];
        t = fmaxf(t, 0.f);
        #pragma unroll
        for (int c = 0; c < OUTC; ++c) u[c] += t * W2l[j * OUTC + c];
    }
    float m = u[0];
    #pragma unroll
    for (int c = 1; c < OUTC; ++c) m = fmaxf(m, u[c]);
    float sum = 0.f;
    #pragma unroll
    for (int c = 0; c < OUTC; ++c) { u[c] = __expf(u[c] - m); sum += u[c]; }
    float inv = 1.f / sum;
    float4* dst4 = (float4*)(out + (size_t)n * OUTC);
    #pragma unroll
    for (int i = 0; i < 4; ++i) {
        float4 v;
        v.x = u[4*i+0] * inv; v.y = u[4*i+1] * inv;
        v.z = u[4*i+2] * inv; v.w = u[4*i+3] * inv;
        dst4[i] = v;
    }
}

extern "C" void kernel_launch(void* const* d_in, const int* in_sizes, int n_in,
                              void* d_out, int out_size, void* d_ws, size_t ws_size,
                              hipStream_t stream)
{
    const float* x      = (const float*)d_in[0];
    const int*   ei     = (const int*)  d_in[1];
    const float* W1     = (const float*)d_in[2];
    const float* a_src1 = (const float*)d_in[3];
    const float* a_dst1 = (const float*)d_in[4];
    const float* b1     = (const float*)d_in[5];
    const float* W2     = (const float*)d_in[6];
    const float* a_src2 = (const float*)d_in[7];
    const float* a_dst2 = (const float*)d_in[8];
    const float* b2     = (const float*)d_in[9];
    const float* lin1W  = (const float*)d_in[10];
    const float* lin1b  = (const float*)d_in[11];
    const float* lin2W  = (const float*)d_in[12];
    const float* lin2b  = (const float*)d_in[13];
    float* out = (float*)d_out;

    int N = in_sizes[0] / FIN;
    int E = in_sizes[1] / 2;
    int tot = E + N;
    int nb = (N + 255) >> BSH;
    int ntile = (tot + 4095) / 4096;

    float* ws = (float*)d_ws;
    size_t off = 0;
    __half* h1 = (__half*)(ws + off); off += (size_t)N * HID / 2;   // fp16 h1
    float* out1  = ws + off; off += (size_t)N * HID;   // pairs aliases this region
    float* as1   = ws + off; off += N;
    float* ad1   = ws + off; off += N;
    float* h2    = ws + off; off += (size_t)N * OUTC;
    float* out2  = ws + off; off += (size_t)N * OUTC;
    float* as2   = ws + off; off += N;
    float* ad2   = ws + off; off += N;
    float* alpha = ws + off; off += tot;
    float* invden = ws + off; off += N;
    int* rowstart = (int*)(ws + off); off += N;
    int* counts   = (int*)(ws + off); off += N;
    int* ssrc     = (int*)(ws + off); off += tot;
    int* bcnt     = (int*)(ws + off); off += MAXNB;
    int* bstartE  = (int*)(ws + off); off += MAXNB + 1;
    int* bcur     = (int*)(ws + off); off += MAXNB;
    unsigned* pairs = (unsigned*)out1;  // 6.8 MB <= 25.6 MB, consumed before k_gat1 writes out1

    hipMemsetAsync(bcnt, 0, (size_t)nb * sizeof(int), stream);

    // bucketed CSR build (packed 4B records)
    kp_cnt <<<ntile, 256, 0, stream>>>(ei, bcnt, E, N);
    kp_scan<<<1, 512, 0, stream>>>(bcnt, bstartE, bcur, N);
    kp_part<<<ntile, 256, 0, stream>>>(ei, bcur, pairs, E, N);
    kc_fine<<<nb, 256, 0, stream>>>(pairs, bstartE, rowstart, counts, ssrc, N);

    // layer 1
    k1_gemm1<<<(N + R1 - 1) / R1, 256, 0, stream>>>(x, W1, a_src1, a_dst1, h1, as1, ad1, N);
    k_wnorm <<<(N + 255) / 256, 256, 0, stream>>>(rowstart, counts, ssrc, as1, ad1, alpha, invden, N);
    k_gat1  <<<(N + 3) / 4, 256, 0, stream>>>(rowstart, counts, ssrc, alpha, invden, h1, out1, N);

    // layer 2
    k4_gemm2<<<(N + 15) / 16, 256, 0, stream>>>(out1, b1, W2, a_src2, a_dst2, h2, as2, ad2, N);
    k_wnorm <<<(N + 255) / 256, 256, 0, stream>>>(rowstart, counts, ssrc, as2, ad2, alpha, invden, N);
    k_gat2  <<<(N + 3) / 4, 256, 0, stream>>>(rowstart, counts, ssrc, alpha, invden, h2, out2, N);

    // MLP + softmax
    k7_mlp<<<(N + 255) / 256, 256, 0, stream>>>(out2, b2, lin1W, lin1b, lin2W, lin2b, out, N);
}